// Round 3
// baseline (602.290 us; speedup 1.0000x reference)
//
#include <hip/hip_runtime.h>

#define B_TOT 65536
#define SEQ   32

typedef __bf16 bf16_8 __attribute__((ext_vector_type(8)));
typedef __bf16 bf16_4 __attribute__((ext_vector_type(4)));
typedef float  float4v __attribute__((ext_vector_type(4)));
typedef float  float2v __attribute__((ext_vector_type(2)));

#define SC1 (-1.4426950408889634f)   // -log2(e): i,f,o gate rows
#define SC2 (-2.8853900817779268f)   // -2*log2(e): g gate rows (and tanh(c2))

__device__ inline unsigned short f2bf(float f){
    unsigned u = __builtin_bit_cast(unsigned, f);
    u += 0x7FFFu + ((u >> 16) & 1u);           // round-to-nearest-even
    return (unsigned short)(u >> 16);
}

__device__ inline float2v v_exp2(float2v x){
    float2v r; r[0] = __builtin_amdgcn_exp2f(x[0]); r[1] = __builtin_amdgcn_exp2f(x[1]); return r;
}
__device__ inline float2v v_rcp(float2v x){
    float2v r; r[0] = __builtin_amdgcn_rcpf(x[0]); r[1] = __builtin_amdgcn_rcpf(x[1]); return r;
}
__device__ inline float2v v_fma(float2v a, float2v b, float2v c){
    float2v r; r[0] = __builtin_fmaf(a[0], b[0], c[0]); r[1] = __builtin_fmaf(a[1], b[1], c[1]); return r;
}

// ---- prep: W_eff = w_hh.T + w_pos.T @ (w_emb.T @ w_ih.T); biases folded;
// rows pre-scaled by -log2e (i,f,o) / -2log2e (g) so exp2 needs no mul. ----
__global__ void prep_kernel(const float* __restrict__ w_ih,
                            const float* __restrict__ w_hh,
                            const float* __restrict__ b_ih,
                            const float* __restrict__ b_hh,
                            const float* __restrict__ w_emb,
                            const float* __restrict__ b_emb,
                            const float* __restrict__ w_pos,
                            const float* __restrict__ b_pos,
                            unsigned short* __restrict__ weff,
                            float* __restrict__ beff,
                            float* __restrict__ m2,
                            unsigned short* __restrict__ wposA)
{
    int n = threadIdx.x;                       // 512 threads, one gate row each
    float m20 = 0.f, m21 = 0.f, bi = 0.f;
    for (int e = 0; e < 64; ++e){
        float wv = w_ih[n*64 + e];
        m20 += w_emb[e*2 + 0] * wv;
        m21 += w_emb[e*2 + 1] * wv;
        bi  += b_emb[e] * wv;
    }
    float sc = ((n >> 7) == 2) ? SC2 : SC1;    // gate order [i,f,g,o]
    m2[n]       = m20 * sc;
    m2[512 + n] = m21 * sc;
    beff[n] = (b_ih[n] + b_hh[n] + bi + b_pos[0]*m20 + b_pos[1]*m21) * sc;
    for (int k = 0; k < 128; ++k){
        float wv = w_hh[n*128 + k] + w_pos[k]*m20 + w_pos[128 + k]*m21;
        weff[n*128 + k] = f2bf(wv * sc);
    }
    if (n < 256) wposA[n] = f2bf(w_pos[n]);    // unscaled: rel path
    for (int idx = n; idx < 14*128; idx += 512) wposA[256 + idx] = 0;
}

// ---- main decoder: 2 batch-tiles (A,B) PER WAVE, half-step offset.
// While tile A runs elementwise (VALU/trans), the same wave issues tile B's
// gate-MFMAs -> deterministic MFMA/VALU overlap. 1 wave/SIMD by design. ----
__global__ __launch_bounds__(256, 1) void dec_kernel(
    const float* __restrict__ lpr,             // (B,2)
    const float* __restrict__ hh,              // (B,128)
    const float* __restrict__ ch,              // (B,128)
    const float* __restrict__ b_pos,           // (2)
    const unsigned short* __restrict__ wposA,  // (16,128) bf16
    const unsigned short* __restrict__ weff,   // (512,128) bf16 pre-scaled
    const float* __restrict__ beff,            // (512) pre-scaled
    const float* __restrict__ m2,              // (2,512) pre-scaled
    float* __restrict__ out)                   // rels (32,B,2) ++ h (B,128)
{
    __shared__ __align__(16) unsigned short lhA[16][152];  // stride 152: <=2-way banks
    __shared__ __align__(16) unsigned short lhB[16][152];
    __shared__ float ubuf[32][2];
    __shared__ __align__(16) float hsh[32][132];           // final-h staging

    const int tid  = threadIdx.x;
    const int w    = tid >> 6;
    const int lane = tid & 63;
    const int q    = lane >> 4;
    const int l    = lane & 15;
    const int row0 = blockIdx.x << 5;          // 32 batches per block
    const int batchA = row0 + l;
    const int batchB = row0 + 16 + l;

    const float2v one2 = {1.f, 1.f};
    const float2v sc22 = {SC2, SC2};

    // resident W_eff A-frags + bias float4s (shared by both tiles)
    bf16_8 wA[8][4];
    float4v bias4[8];
#pragma unroll
    for (int t8 = 0; t8 < 8; ++t8){
        int nbase = ((t8 >> 1) << 7) + 32*w + ((t8 & 1) << 4);
        int gA = nbase + l;
#pragma unroll
        for (int kt = 0; kt < 4; ++kt)
            wA[t8][kt] = *(const bf16_8*)(weff + (gA << 7) + kt*32 + (q << 3));
        bias4[t8] = *(const float4v*)(beff + nbase + (q << 2));
    }

    bf16_8 wpA[4];
#pragma unroll
    for (int kt = 0; kt < 4; ++kt)
        wpA[kt] = *(const bf16_8*)(wposA + (l << 7) + kt*32 + (q << 3));
    const float bp0 = b_pos[0], bp1 = b_pos[1];

    // c state for both tiles
    float2v cstA[2][2], cstB[2][2];
#pragma unroll
    for (int X = 0; X < 2; ++X){
        float4v ca = *(const float4v*)(ch + (batchA << 7) + 32*w + 16*X + (q << 2));
        float4v cb = *(const float4v*)(ch + (batchB << 7) + 32*w + 16*X + (q << 2));
        float2v t;
        t[0]=ca[0]; t[1]=ca[1]; cstA[X][0]=t;
        t[0]=ca[2]; t[1]=ca[3]; cstA[X][1]=t;
        t[0]=cb[0]; t[1]=cb[1]; cstB[X][0]=t;
        t[0]=cb[2]; t[1]=cb[3]; cstB[X][1]=t;
    }

    // h0 B-frags for both tiles (fp32 -> bf16)
    bf16_8 bA[4], bB[4];
#pragma unroll
    for (int kt = 0; kt < 4; ++kt){
        const float* pa = hh + (batchA << 7) + kt*32 + (q << 3);
        const float* pb = hh + (batchB << 7) + kt*32 + (q << 3);
        float4v a0 = *(const float4v*)pa;      float4v a1 = *(const float4v*)(pa + 4);
        float4v c0 = *(const float4v*)pb;      float4v c1 = *(const float4v*)(pb + 4);
        bf16_8 ta, tb;
        ta[0]=(__bf16)a0[0]; ta[1]=(__bf16)a0[1]; ta[2]=(__bf16)a0[2]; ta[3]=(__bf16)a0[3];
        ta[4]=(__bf16)a1[0]; ta[5]=(__bf16)a1[1]; ta[6]=(__bf16)a1[2]; ta[7]=(__bf16)a1[3];
        tb[0]=(__bf16)c0[0]; tb[1]=(__bf16)c0[1]; tb[2]=(__bf16)c0[2]; tb[3]=(__bf16)c0[3];
        tb[4]=(__bf16)c1[0]; tb[5]=(__bf16)c1[1]; tb[6]=(__bf16)c1[2]; tb[7]=(__bf16)c1[3];
        bA[kt] = ta;
        bB[kt] = tb;
    }

    // prologue: r_{-1} = w_pos·h0 + b_pos per tile; u0' = lpr - r_{-1}
    if (w == 0){
        float4v r = {0.f, 0.f, 0.f, 0.f};
#pragma unroll
        for (int kt = 0; kt < 4; ++kt)
            r = __builtin_amdgcn_mfma_f32_16x16x32_bf16(wpA[kt], bA[kt], r, 0, 0, 0);
        if (q == 0){
            float2v lp = *(const float2v*)(lpr + (batchA << 1));
            ubuf[l][0] = lp[0] - (r[0] + bp0);
            ubuf[l][1] = lp[1] - (r[1] + bp1);
        }
    }
    if (w == 1){
        float4v r = {0.f, 0.f, 0.f, 0.f};
#pragma unroll
        for (int kt = 0; kt < 4; ++kt)
            r = __builtin_amdgcn_mfma_f32_16x16x32_bf16(wpA[kt], bB[kt], r, 0, 0, 0);
        if (q == 0){
            float2v lp = *(const float2v*)(lpr + (batchB << 1));
            ubuf[16 + l][0] = lp[0] - (r[0] + bp0);
            ubuf[16 + l][1] = lp[1] - (r[1] + bp1);
        }
    }
    __syncthreads();

    float4v accA[8], accB[8];

    auto do_gates = [&](float4v (&acc)[8], bf16_8 (&b)[4]){
#pragma unroll
        for (int t8 = 0; t8 < 8; ++t8)     // kt=0 consumes bias as C: free init
            acc[t8] = __builtin_amdgcn_mfma_f32_16x16x32_bf16(wA[t8][0], b[0], bias4[t8], 0, 0, 0);
#pragma unroll
        for (int kt = 1; kt < 4; ++kt)
#pragma unroll
            for (int t8 = 0; t8 < 8; ++t8)
                acc[t8] = __builtin_amdgcn_mfma_f32_16x16x32_bf16(wA[t8][kt], b[kt], acc[t8], 0, 0, 0);
    };

    auto u0fix = [&](float4v (&acc)[8], int ur){
        float u0 = ubuf[ur][0], u1 = ubuf[ur][1];
#pragma unroll
        for (int t8 = 0; t8 < 8; ++t8){
            int g0 = ((t8 >> 1) << 7) + 32*w + ((t8 & 1) << 4) + (q << 2);
            float4v ma = *(const float4v*)(m2 + g0);
            float4v mb = *(const float4v*)(m2 + 512 + g0);
#pragma unroll
            for (int r4 = 0; r4 < 4; ++r4)
                acc[t8][r4] += u0*ma[r4] + u1*mb[r4];
        }
    };

    // merged-reciprocal LSTM cell, pairwise v2f32 (verified round 2)
    auto elem_write = [&](float4v (&acc)[8], float2v (&cst)[2][2],
                          unsigned short (*lhp)[152], bool finalh, int hrow){
#pragma unroll
        for (int X = 0; X < 2; ++X){
            bf16_4 hv;
#pragma unroll
            for (int p = 0; p < 2; ++p){
                float2v iv = {acc[0 + X][2*p], acc[0 + X][2*p + 1]};
                float2v fv = {acc[2 + X][2*p], acc[2 + X][2*p + 1]};
                float2v gv = {acc[4 + X][2*p], acc[4 + X][2*p + 1]};
                float2v ov = {acc[6 + X][2*p], acc[6 + X][2*p + 1]};
                float2v ei = v_exp2(iv);                  // e^{-i}
                float2v ef = v_exp2(fv);                  // e^{-f}
                float2v eg = v_exp2(gv);                  // e^{-2g}
                float2v pi_ = ei + one2;
                float2v pf  = ef + one2;
                float2v pg  = eg + one2;
                float2v mg  = one2 - eg;
                float2v t2  = pi_ * pg;
                float2v den = pf * t2;
                float2v num = v_fma(cst[X][p], t2, pf * mg);
                float2v c2  = num * v_rcp(den);
                float2v eo  = v_exp2(ov);                 // e^{-o}
                float2v ec  = v_exp2(c2 * sc22);          // e^{-2c2}
                float2v po  = eo + one2;
                float2v pc  = ec + one2;
                float2v mc  = one2 - ec;
                float2v h2  = mc * v_rcp(po * pc);
                cst[X][p] = c2;
                hv[2*p]     = (__bf16)h2[0];
                hv[2*p + 1] = (__bf16)h2[1];
                if (finalh){
                    int cb = 32*w + 16*X + (q << 2) + 2*p;
                    hsh[hrow][cb]     = h2[0];
                    hsh[hrow][cb + 1] = h2[1];
                }
            }
            *(bf16_4*)&lhp[l][32*w + 16*X + (q << 2)] = hv;   // packed b64
        }
    };

    auto reload = [&](bf16_8 (&b)[4], const unsigned short (*lhp)[152]){
#pragma unroll
        for (int kt = 0; kt < 4; ++kt)
            b[kt] = *(const bf16_8*)&lhp[l][kt*32 + (q << 3)];
    };

    auto relout = [&](bf16_8 (&b)[4], int t, int batch){
        float4v r = {0.f, 0.f, 0.f, 0.f};
#pragma unroll
        for (int kt = 0; kt < 4; ++kt)
            r = __builtin_amdgcn_mfma_f32_16x16x32_bf16(wpA[kt], b[kt], r, 0, 0, 0);
        if (q == 0){
            float2v rv;
            rv[0] = r[0] + bp0;
            rv[1] = r[1] + bp1;
            *(float2v*)(out + t*(B_TOT*2) + (batch << 1)) = rv;
        }
    };

    // ---- software pipeline: tiles A and B offset by half a step ----
    do_gates(accA, bA);
    u0fix(accA, l);

    for (int t = 0; t < SEQ; ++t){
        // region 1: gates(B,t) [MFMA] overlapped with elem(A,t) [VALU/trans]
        do_gates(accB, bB);
        if (t == 0) u0fix(accB, 16 + l);
        elem_write(accA, cstA, lhA, t == SEQ - 1, l);
        __syncthreads();
        reload(bA, lhA);
        if (w == (t & 3)) relout(bA, t, batchA);
        // region 2: gates(A,t+1) overlapped with elem(B,t)
        if (t < SEQ - 1) do_gates(accA, bA);
        elem_write(accB, cstB, lhB, t == SEQ - 1, 16 + l);
        __syncthreads();
        reload(bB, lhB);
        if (w == ((t + 2) & 3)) relout(bB, t, batchB);
    }

    // ---- coalesced final-h store: LDS-staged ----
    __syncthreads();
    {
        int r = tid >> 3, c16 = (tid & 7) << 4;   // 32 rows x 128 cols
        float4v v0 = *(const float4v*)&hsh[r][c16];
        float4v v1 = *(const float4v*)&hsh[r][c16 + 4];
        float4v v2 = *(const float4v*)&hsh[r][c16 + 8];
        float4v v3 = *(const float4v*)&hsh[r][c16 + 12];
        float* po = out + SEQ*B_TOT*2 + ((row0 + r) << 7) + c16;
        *(float4v*)po = v0;
        *(float4v*)(po + 4)  = v1;
        *(float4v*)(po + 8)  = v2;
        *(float4v*)(po + 12) = v3;
    }
}

extern "C" void kernel_launch(void* const* d_in, const int* in_sizes, int n_in,
                              void* d_out, int out_size, void* d_ws, size_t ws_size,
                              hipStream_t stream)
{
    (void)in_sizes; (void)n_in; (void)out_size; (void)ws_size;

    const float* lpr   = (const float*)d_in[1];
    const float* hh    = (const float*)d_in[2];
    const float* ch    = (const float*)d_in[3];
    const float* w_ih  = (const float*)d_in[5];
    const float* w_hh  = (const float*)d_in[6];
    const float* b_ih  = (const float*)d_in[7];
    const float* b_hh  = (const float*)d_in[8];
    const float* w_emb = (const float*)d_in[9];
    const float* b_emb = (const float*)d_in[10];
    const float* w_pos = (const float*)d_in[11];
    const float* b_pos = (const float*)d_in[12];

    unsigned short* weff  = (unsigned short*)d_ws;                     // 512*128 bf16
    float* beff           = (float*)((char*)d_ws + 131072);            // 512 f32
    float* m2             = (float*)((char*)d_ws + 131072 + 2048);     // 1024 f32
    unsigned short* wposA = (unsigned short*)((char*)d_ws + 131072 + 2048 + 4096); // 16*128 bf16

    hipLaunchKernelGGL(prep_kernel, dim3(1), dim3(512), 0, stream,
                       w_ih, w_hh, b_ih, b_hh, w_emb, b_emb, w_pos, b_pos,
                       weff, beff, m2, wposA);
    hipLaunchKernelGGL(dec_kernel, dim3(B_TOT/32), dim3(256), 0, stream,
                       lpr, hh, ch, b_pos, wposA, weff, beff, m2,
                       (float*)d_out);
}

// Round 4
// 566.842 us; speedup vs baseline: 1.0625x; 1.0625x over previous
//
#include <hip/hip_runtime.h>

#define B_TOT 65536
#define SEQ   32

typedef __bf16 bf16_8 __attribute__((ext_vector_type(8)));
typedef __bf16 bf16_4 __attribute__((ext_vector_type(4)));
typedef float  float4v __attribute__((ext_vector_type(4)));
typedef float  float2v __attribute__((ext_vector_type(2)));

#define SC1 (-1.4426950408889634f)   // -log2(e): i,f,o gate rows
#define SC2 (-2.8853900817779268f)   // -2*log2(e): g gate rows (and tanh(c2))

__device__ inline unsigned short f2bf(float f){
    unsigned u = __builtin_bit_cast(unsigned, f);
    u += 0x7FFFu + ((u >> 16) & 1u);           // round-to-nearest-even
    return (unsigned short)(u >> 16);
}

__device__ inline float2v v_exp2(float2v x){
    float2v r; r[0] = __builtin_amdgcn_exp2f(x[0]); r[1] = __builtin_amdgcn_exp2f(x[1]); return r;
}
__device__ inline float2v v_rcp(float2v x){
    float2v r; r[0] = __builtin_amdgcn_rcpf(x[0]); r[1] = __builtin_amdgcn_rcpf(x[1]); return r;
}
__device__ inline float2v v_fma(float2v a, float2v b, float2v c){
    float2v r; r[0] = __builtin_fmaf(a[0], b[0], c[0]); r[1] = __builtin_fmaf(a[1], b[1], c[1]); return r;
}

// ---- prep: W_eff = w_hh.T + w_pos.T @ (w_emb.T @ w_ih.T); biases folded;
// rows pre-scaled by -log2e (i,f,o) / -2log2e (g) so exp2 needs no mul. ----
__global__ void prep_kernel(const float* __restrict__ w_ih,
                            const float* __restrict__ w_hh,
                            const float* __restrict__ b_ih,
                            const float* __restrict__ b_hh,
                            const float* __restrict__ w_emb,
                            const float* __restrict__ b_emb,
                            const float* __restrict__ w_pos,
                            const float* __restrict__ b_pos,
                            unsigned short* __restrict__ weff,
                            float* __restrict__ beff,
                            float* __restrict__ m2,
                            unsigned short* __restrict__ wposA)
{
    int n = threadIdx.x;                       // 512 threads, one gate row each
    float m20 = 0.f, m21 = 0.f, bi = 0.f;
    for (int e = 0; e < 64; ++e){
        float wv = w_ih[n*64 + e];
        m20 += w_emb[e*2 + 0] * wv;
        m21 += w_emb[e*2 + 1] * wv;
        bi  += b_emb[e] * wv;
    }
    float sc = ((n >> 7) == 2) ? SC2 : SC1;    // gate order [i,f,g,o]
    m2[n]       = m20 * sc;
    m2[512 + n] = m21 * sc;
    beff[n] = (b_ih[n] + b_hh[n] + bi + b_pos[0]*m20 + b_pos[1]*m21) * sc;
    for (int k = 0; k < 128; ++k){
        float wv = w_hh[n*128 + k] + w_pos[k]*m20 + w_pos[128 + k]*m21;
        weff[n*128 + k] = f2bf(wv * sc);
    }
    if (n < 256) wposA[n] = f2bf(w_pos[n]);    // unscaled: rel path
    for (int idx = n; idx < 14*128; idx += 512) wposA[256 + idx] = 0;
}

// ---- main decoder: 512 threads / 8 waves; each wave owns 16 h-units
// (64 gate rows, all 4 gates) -> wA is 64 VGPRs, leaving room for TWO
// batch-tiles (A,B) per wave at 2 waves/SIMD. A/B run half-step offset:
// gates(B) MFMAs interleave with elem(A) VALU/trans in-wave, while
// 2 waves/SIMD provide cross-wave latency hiding (round-2 TLP). ----
__global__ __launch_bounds__(512, 2) void dec_kernel(
    const float* __restrict__ lpr,             // (B,2)
    const float* __restrict__ hh,              // (B,128)
    const float* __restrict__ ch,              // (B,128)
    const float* __restrict__ b_pos,           // (2)
    const unsigned short* __restrict__ wposA,  // (16,128) bf16
    const unsigned short* __restrict__ weff,   // (512,128) bf16 pre-scaled
    const float* __restrict__ beff,            // (512) pre-scaled
    const float* __restrict__ m2,              // (2,512) pre-scaled
    float* __restrict__ out)                   // rels (32,B,2) ++ h (B,128)
{
    __shared__ __align__(16) unsigned short lhA[16][152];  // stride 152: <=2-way banks
    __shared__ __align__(16) unsigned short lhB[16][152];
    __shared__ float ubuf[32][2];
    __shared__ __align__(16) float hsh[32][132];           // final-h staging

    const int tid  = threadIdx.x;
    const int w    = tid >> 6;                 // 0..7
    const int lane = tid & 63;
    const int q    = lane >> 4;
    const int l    = lane & 15;
    const int row0 = blockIdx.x << 5;          // 32 batches per block
    const int batchA = row0 + l;
    const int batchB = row0 + 16 + l;

    const float2v one2 = {1.f, 1.f};
    const float2v sc22 = {SC2, SC2};

    // resident W_eff A-frags: 4 gates x 16 units (rows g*128 + 16w .. +15)
    bf16_8 wA[4][4];
    float4v bias4[4];
#pragma unroll
    for (int g = 0; g < 4; ++g){
        int nbase = (g << 7) + (w << 4);
        int gA = nbase + l;
#pragma unroll
        for (int kt = 0; kt < 4; ++kt)
            wA[g][kt] = *(const bf16_8*)(weff + (gA << 7) + kt*32 + (q << 3));
        bias4[g] = *(const float4v*)(beff + nbase + (q << 2));
    }

    bf16_8 wpA[4];
#pragma unroll
    for (int kt = 0; kt < 4; ++kt)
        wpA[kt] = *(const bf16_8*)(wposA + (l << 7) + kt*32 + (q << 3));
    const float bp0 = b_pos[0], bp1 = b_pos[1];

    // c state: units 16w+4q+{0..3} for batch l, per tile
    float2v cstA[2], cstB[2];
    {
        float4v ca = *(const float4v*)(ch + (batchA << 7) + (w << 4) + (q << 2));
        float4v cb = *(const float4v*)(ch + (batchB << 7) + (w << 4) + (q << 2));
        float2v t;
        t[0]=ca[0]; t[1]=ca[1]; cstA[0]=t;
        t[0]=ca[2]; t[1]=ca[3]; cstA[1]=t;
        t[0]=cb[0]; t[1]=cb[1]; cstB[0]=t;
        t[0]=cb[2]; t[1]=cb[3]; cstB[1]=t;
    }

    // h0 B-frags for both tiles (fp32 -> bf16); each lane: full 128 cols of its batch
    bf16_8 bA[4], bB[4];
#pragma unroll
    for (int kt = 0; kt < 4; ++kt){
        const float* pa = hh + (batchA << 7) + kt*32 + (q << 3);
        const float* pb = hh + (batchB << 7) + kt*32 + (q << 3);
        float4v a0 = *(const float4v*)pa;      float4v a1 = *(const float4v*)(pa + 4);
        float4v c0 = *(const float4v*)pb;      float4v c1 = *(const float4v*)(pb + 4);
        bf16_8 ta, tb;
        ta[0]=(__bf16)a0[0]; ta[1]=(__bf16)a0[1]; ta[2]=(__bf16)a0[2]; ta[3]=(__bf16)a0[3];
        ta[4]=(__bf16)a1[0]; ta[5]=(__bf16)a1[1]; ta[6]=(__bf16)a1[2]; ta[7]=(__bf16)a1[3];
        tb[0]=(__bf16)c0[0]; tb[1]=(__bf16)c0[1]; tb[2]=(__bf16)c0[2]; tb[3]=(__bf16)c0[3];
        tb[4]=(__bf16)c1[0]; tb[5]=(__bf16)c1[1]; tb[6]=(__bf16)c1[2]; tb[7]=(__bf16)c1[3];
        bA[kt] = ta;
        bB[kt] = tb;
    }

    // prologue: r_{-1} = w_pos·h0 + b_pos per tile; u0' = lpr - r_{-1}
    if (w == 0){
        float4v r = {0.f, 0.f, 0.f, 0.f};
#pragma unroll
        for (int kt = 0; kt < 4; ++kt)
            r = __builtin_amdgcn_mfma_f32_16x16x32_bf16(wpA[kt], bA[kt], r, 0, 0, 0);
        if (q == 0){
            float2v lp = *(const float2v*)(lpr + (batchA << 1));
            ubuf[l][0] = lp[0] - (r[0] + bp0);
            ubuf[l][1] = lp[1] - (r[1] + bp1);
        }
    }
    if (w == 1){
        float4v r = {0.f, 0.f, 0.f, 0.f};
#pragma unroll
        for (int kt = 0; kt < 4; ++kt)
            r = __builtin_amdgcn_mfma_f32_16x16x32_bf16(wpA[kt], bB[kt], r, 0, 0, 0);
        if (q == 0){
            float2v lp = *(const float2v*)(lpr + (batchB << 1));
            ubuf[16 + l][0] = lp[0] - (r[0] + bp0);
            ubuf[16 + l][1] = lp[1] - (r[1] + bp1);
        }
    }
    __syncthreads();

    float4v accA[4], accB[4];

    auto do_gates = [&](float4v (&acc)[4], bf16_8 (&b)[4]){
#pragma unroll
        for (int g = 0; g < 4; ++g)        // kt=0 consumes bias as C: free init
            acc[g] = __builtin_amdgcn_mfma_f32_16x16x32_bf16(wA[g][0], b[0], bias4[g], 0, 0, 0);
#pragma unroll
        for (int kt = 1; kt < 4; ++kt)
#pragma unroll
            for (int g = 0; g < 4; ++g)
                acc[g] = __builtin_amdgcn_mfma_f32_16x16x32_bf16(wA[g][kt], b[kt], acc[g], 0, 0, 0);
    };

    auto u0fix = [&](float4v (&acc)[4], int ur){
        float u0 = ubuf[ur][0], u1 = ubuf[ur][1];
#pragma unroll
        for (int g = 0; g < 4; ++g){
            int g0 = (g << 7) + (w << 4) + (q << 2);
            float4v ma = *(const float4v*)(m2 + g0);
            float4v mb = *(const float4v*)(m2 + 512 + g0);
#pragma unroll
            for (int r4 = 0; r4 < 4; ++r4)
                acc[g][r4] += u0*ma[r4] + u1*mb[r4];
        }
    };

    // merged-reciprocal LSTM cell, pairwise v2f32 (verified round 2)
    auto elem_write = [&](float4v (&acc)[4], float2v (&cst)[2],
                          unsigned short (*lhp)[152], bool finalh, int hrow){
        bf16_4 hv;
#pragma unroll
        for (int p = 0; p < 2; ++p){
            float2v iv = {acc[0][2*p], acc[0][2*p + 1]};
            float2v fv = {acc[1][2*p], acc[1][2*p + 1]};
            float2v gv = {acc[2][2*p], acc[2][2*p + 1]};
            float2v ov = {acc[3][2*p], acc[3][2*p + 1]};
            float2v ei = v_exp2(iv);                  // e^{-i}
            float2v ef = v_exp2(fv);                  // e^{-f}
            float2v eg = v_exp2(gv);                  // e^{-2g}
            float2v pi_ = ei + one2;
            float2v pf  = ef + one2;
            float2v pg  = eg + one2;
            float2v mg  = one2 - eg;
            float2v t2  = pi_ * pg;
            float2v den = pf * t2;
            float2v num = v_fma(cst[p], t2, pf * mg);
            float2v c2  = num * v_rcp(den);
            float2v eo  = v_exp2(ov);                 // e^{-o}
            float2v ec  = v_exp2(c2 * sc22);          // e^{-2c2}
            float2v po  = eo + one2;
            float2v pc  = ec + one2;
            float2v mc  = one2 - ec;
            float2v h2  = mc * v_rcp(po * pc);
            cst[p] = c2;
            hv[2*p]     = (__bf16)h2[0];
            hv[2*p + 1] = (__bf16)h2[1];
            if (finalh){
                int cb = (w << 4) + (q << 2) + 2*p;
                hsh[hrow][cb]     = h2[0];
                hsh[hrow][cb + 1] = h2[1];
            }
        }
        *(bf16_4*)&lhp[l][(w << 4) + (q << 2)] = hv;   // packed b64
    };

    auto reload = [&](bf16_8 (&b)[4], const unsigned short (*lhp)[152]){
#pragma unroll
        for (int kt = 0; kt < 4; ++kt)
            b[kt] = *(const bf16_8*)&lhp[l][kt*32 + (q << 3)];
    };

    auto relout = [&](bf16_8 (&b)[4], int t, int batch){
        float4v r = {0.f, 0.f, 0.f, 0.f};
#pragma unroll
        for (int kt = 0; kt < 4; ++kt)
            r = __builtin_amdgcn_mfma_f32_16x16x32_bf16(wpA[kt], b[kt], r, 0, 0, 0);
        if (q == 0){
            float2v rv;
            rv[0] = r[0] + bp0;
            rv[1] = r[1] + bp1;
            *(float2v*)(out + t*(B_TOT*2) + (batch << 1)) = rv;
        }
    };

    // ---- software pipeline: tiles A and B offset by half a step ----
    do_gates(accA, bA);
    u0fix(accA, l);

    for (int t = 0; t < SEQ; ++t){
        // region 1: gates(B,t) [MFMA] overlapped with elem(A,t) [VALU/trans]
        do_gates(accB, bB);
        if (t == 0) u0fix(accB, 16 + l);
        elem_write(accA, cstA, lhA, t == SEQ - 1, l);
        __syncthreads();
        reload(bA, lhA);
        if (w == (t & 7)) relout(bA, t, batchA);
        // region 2: gates(A,t+1) overlapped with elem(B,t)
        if (t < SEQ - 1) do_gates(accA, bA);
        elem_write(accB, cstB, lhB, t == SEQ - 1, 16 + l);
        __syncthreads();
        reload(bB, lhB);
        if (w == ((t + 4) & 7)) relout(bB, t, batchB);
    }

    // ---- coalesced final-h store: LDS-staged, 32 rows x 128 cols ----
    __syncthreads();
    {
        int r = tid >> 4, c8 = (tid & 15) << 3;
        float4v v0 = *(const float4v*)&hsh[r][c8];
        float4v v1 = *(const float4v*)&hsh[r][c8 + 4];
        float* po = out + SEQ*B_TOT*2 + ((row0 + r) << 7) + c8;
        *(float4v*)po = v0;
        *(float4v*)(po + 4) = v1;
    }
}

extern "C" void kernel_launch(void* const* d_in, const int* in_sizes, int n_in,
                              void* d_out, int out_size, void* d_ws, size_t ws_size,
                              hipStream_t stream)
{
    (void)in_sizes; (void)n_in; (void)out_size; (void)ws_size;

    const float* lpr   = (const float*)d_in[1];
    const float* hh    = (const float*)d_in[2];
    const float* ch    = (const float*)d_in[3];
    const float* w_ih  = (const float*)d_in[5];
    const float* w_hh  = (const float*)d_in[6];
    const float* b_ih  = (const float*)d_in[7];
    const float* b_hh  = (const float*)d_in[8];
    const float* w_emb = (const float*)d_in[9];
    const float* b_emb = (const float*)d_in[10];
    const float* w_pos = (const float*)d_in[11];
    const float* b_pos = (const float*)d_in[12];

    unsigned short* weff  = (unsigned short*)d_ws;                     // 512*128 bf16
    float* beff           = (float*)((char*)d_ws + 131072);            // 512 f32
    float* m2             = (float*)((char*)d_ws + 131072 + 2048);     // 1024 f32
    unsigned short* wposA = (unsigned short*)((char*)d_ws + 131072 + 2048 + 4096); // 16*128 bf16

    hipLaunchKernelGGL(prep_kernel, dim3(1), dim3(512), 0, stream,
                       w_ih, w_hh, b_ih, b_hh, w_emb, b_emb, w_pos, b_pos,
                       weff, beff, m2, wposA);
    hipLaunchKernelGGL(dec_kernel, dim3(B_TOT/32), dim3(512), 0, stream,
                       lpr, hh, ch, b_pos, wposA, weff, beff, m2,
                       (float*)d_out);
}

// Round 5
// 561.624 us; speedup vs baseline: 1.0724x; 1.0093x over previous
//
#include <hip/hip_runtime.h>

#define B_TOT 65536
#define SEQ   32

typedef __bf16 bf16_8 __attribute__((ext_vector_type(8)));
typedef __bf16 bf16_4 __attribute__((ext_vector_type(4)));
typedef float  float4v __attribute__((ext_vector_type(4)));
typedef float  float2v __attribute__((ext_vector_type(2)));

#define SC1 (-1.4426950408889634f)   // -log2(e): i,f,o gate rows
#define SC2 (-2.8853900817779268f)   // -2*log2(e): g gate rows (and tanh(c2))

__device__ inline unsigned short f2bf(float f){
    unsigned u = __builtin_bit_cast(unsigned, f);
    u += 0x7FFFu + ((u >> 16) & 1u);           // round-to-nearest-even
    return (unsigned short)(u >> 16);
}

__device__ inline float2v v_exp2(float2v x){
    float2v r; r[0] = __builtin_amdgcn_exp2f(x[0]); r[1] = __builtin_amdgcn_exp2f(x[1]); return r;
}
__device__ inline float2v v_rcp(float2v x){
    float2v r; r[0] = __builtin_amdgcn_rcpf(x[0]); r[1] = __builtin_amdgcn_rcpf(x[1]); return r;
}
__device__ inline float2v v_fma(float2v a, float2v b, float2v c){
    float2v r; r[0] = __builtin_fmaf(a[0], b[0], c[0]); r[1] = __builtin_fmaf(a[1], b[1], c[1]); return r;
}

// ---- prep: W_eff = w_hh.T + w_pos.T @ (w_emb.T @ w_ih.T); biases folded;
// rows pre-scaled by -log2e (i,f,o) / -2log2e (g) so exp2 needs no mul. ----
__global__ void prep_kernel(const float* __restrict__ w_ih,
                            const float* __restrict__ w_hh,
                            const float* __restrict__ b_ih,
                            const float* __restrict__ b_hh,
                            const float* __restrict__ w_emb,
                            const float* __restrict__ b_emb,
                            const float* __restrict__ w_pos,
                            const float* __restrict__ b_pos,
                            unsigned short* __restrict__ weff,
                            float* __restrict__ beff,
                            float* __restrict__ m2,
                            unsigned short* __restrict__ wposA)
{
    int n = threadIdx.x;                       // 512 threads, one gate row each
    float m20 = 0.f, m21 = 0.f, bi = 0.f;
    for (int e = 0; e < 64; ++e){
        float wv = w_ih[n*64 + e];
        m20 += w_emb[e*2 + 0] * wv;
        m21 += w_emb[e*2 + 1] * wv;
        bi  += b_emb[e] * wv;
    }
    float sc = ((n >> 7) == 2) ? SC2 : SC1;    // gate order [i,f,g,o]
    m2[n]       = m20 * sc;
    m2[512 + n] = m21 * sc;
    beff[n] = (b_ih[n] + b_hh[n] + bi + b_pos[0]*m20 + b_pos[1]*m21) * sc;
    for (int k = 0; k < 128; ++k){
        float wv = w_hh[n*128 + k] + w_pos[k]*m20 + w_pos[128 + k]*m21;
        weff[n*128 + k] = f2bf(wv * sc);
    }
    if (n < 256) wposA[n] = f2bf(w_pos[n]);    // unscaled: rel path
    for (int idx = n; idx < 14*128; idx += 512) wposA[256 + idx] = 0;
}

// ---- main decoder: 512 threads / 8 waves; each wave owns 16 h-units
// (64 gate rows, all 4 gates). TWO batch-tiles (A,B) per wave, half-step
// offset; gate-MFMAs of the next tile are FISSIONED into 8-MFMA chunks
// interleaved with the current tile's elementwise pairs so the in-order
// issue port alternates MFMA-pipe and VALU/trans-pipe work. ----
__global__ __launch_bounds__(512, 2) void dec_kernel(
    const float* __restrict__ lpr,             // (B,2)
    const float* __restrict__ hh,              // (B,128)
    const float* __restrict__ ch,              // (B,128)
    const float* __restrict__ b_pos,           // (2)
    const unsigned short* __restrict__ wposA,  // (16,128) bf16
    const unsigned short* __restrict__ weff,   // (512,128) bf16 pre-scaled
    const float* __restrict__ beff,            // (512) pre-scaled
    const float* __restrict__ m2,              // (2,512) pre-scaled
    float* __restrict__ out)                   // rels (32,B,2) ++ h (B,128)
{
    __shared__ __align__(16) unsigned short lhA[16][152];  // stride 152: <=2-way banks
    __shared__ __align__(16) unsigned short lhB[16][152];
    __shared__ float ubuf[32][2];
    __shared__ __align__(16) float hsh[32][132];           // final-h staging

    const int tid  = threadIdx.x;
    const int w    = tid >> 6;                 // 0..7
    const int lane = tid & 63;
    const int q    = lane >> 4;
    const int l    = lane & 15;
    const int row0 = blockIdx.x << 5;          // 32 batches per block
    const int batchA = row0 + l;
    const int batchB = row0 + 16 + l;

    const float2v one2 = {1.f, 1.f};
    const float2v sc22 = {SC2, SC2};

    // resident W_eff A-frags: 4 gates x 16 units (rows g*128 + 16w .. +15)
    bf16_8 wA[4][4];
    float4v bias4[4];
#pragma unroll
    for (int g = 0; g < 4; ++g){
        int nbase = (g << 7) + (w << 4);
        int gA = nbase + l;
#pragma unroll
        for (int kt = 0; kt < 4; ++kt)
            wA[g][kt] = *(const bf16_8*)(weff + (gA << 7) + kt*32 + (q << 3));
        bias4[g] = *(const float4v*)(beff + nbase + (q << 2));
    }

    bf16_8 wpA[4];
#pragma unroll
    for (int kt = 0; kt < 4; ++kt)
        wpA[kt] = *(const bf16_8*)(wposA + (l << 7) + kt*32 + (q << 3));
    const float bp0 = b_pos[0], bp1 = b_pos[1];

    // c state: units 16w+4q+{0..3} for batch l, per tile
    float2v cstA[2], cstB[2];
    {
        float4v ca = *(const float4v*)(ch + (batchA << 7) + (w << 4) + (q << 2));
        float4v cb = *(const float4v*)(ch + (batchB << 7) + (w << 4) + (q << 2));
        float2v t;
        t[0]=ca[0]; t[1]=ca[1]; cstA[0]=t;
        t[0]=ca[2]; t[1]=ca[3]; cstA[1]=t;
        t[0]=cb[0]; t[1]=cb[1]; cstB[0]=t;
        t[0]=cb[2]; t[1]=cb[3]; cstB[1]=t;
    }

    // h0 B-frags for both tiles (fp32 -> bf16)
    bf16_8 bA[4], bB[4];
#pragma unroll
    for (int kt = 0; kt < 4; ++kt){
        const float* pa = hh + (batchA << 7) + kt*32 + (q << 3);
        const float* pb = hh + (batchB << 7) + kt*32 + (q << 3);
        float4v a0 = *(const float4v*)pa;      float4v a1 = *(const float4v*)(pa + 4);
        float4v c0 = *(const float4v*)pb;      float4v c1 = *(const float4v*)(pb + 4);
        bf16_8 ta, tb;
        ta[0]=(__bf16)a0[0]; ta[1]=(__bf16)a0[1]; ta[2]=(__bf16)a0[2]; ta[3]=(__bf16)a0[3];
        ta[4]=(__bf16)a1[0]; ta[5]=(__bf16)a1[1]; ta[6]=(__bf16)a1[2]; ta[7]=(__bf16)a1[3];
        tb[0]=(__bf16)c0[0]; tb[1]=(__bf16)c0[1]; tb[2]=(__bf16)c0[2]; tb[3]=(__bf16)c0[3];
        tb[4]=(__bf16)c1[0]; tb[5]=(__bf16)c1[1]; tb[6]=(__bf16)c1[2]; tb[7]=(__bf16)c1[3];
        bA[kt] = ta;
        bB[kt] = tb;
    }

    // prologue: r_{-1} = w_pos·h0 + b_pos per tile; u0' = lpr - r_{-1}
    if (w == 0){
        float4v r = {0.f, 0.f, 0.f, 0.f};
#pragma unroll
        for (int kt = 0; kt < 4; ++kt)
            r = __builtin_amdgcn_mfma_f32_16x16x32_bf16(wpA[kt], bA[kt], r, 0, 0, 0);
        if (q == 0){
            float2v lp = *(const float2v*)(lpr + (batchA << 1));
            ubuf[l][0] = lp[0] - (r[0] + bp0);
            ubuf[l][1] = lp[1] - (r[1] + bp1);
        }
    }
    if (w == 1){
        float4v r = {0.f, 0.f, 0.f, 0.f};
#pragma unroll
        for (int kt = 0; kt < 4; ++kt)
            r = __builtin_amdgcn_mfma_f32_16x16x32_bf16(wpA[kt], bB[kt], r, 0, 0, 0);
        if (q == 0){
            float2v lp = *(const float2v*)(lpr + (batchB << 1));
            ubuf[16 + l][0] = lp[0] - (r[0] + bp0);
            ubuf[16 + l][1] = lp[1] - (r[1] + bp1);
        }
    }
    __syncthreads();

    float4v accA[4], accB[4];

    auto do_gates = [&](float4v (&acc)[4], bf16_8 (&b)[4]){
#pragma unroll
        for (int g = 0; g < 4; ++g)        // kt=0 consumes bias as C: free init
            acc[g] = __builtin_amdgcn_mfma_f32_16x16x32_bf16(wA[g][0], b[0], bias4[g], 0, 0, 0);
#pragma unroll
        for (int kt = 1; kt < 4; ++kt)
#pragma unroll
            for (int g = 0; g < 4; ++g)
                acc[g] = __builtin_amdgcn_mfma_f32_16x16x32_bf16(wA[g][kt], b[kt], acc[g], 0, 0, 0);
    };

    auto u0fix = [&](float4v (&acc)[4], int ur){
        float u0 = ubuf[ur][0], u1 = ubuf[ur][1];
#pragma unroll
        for (int g = 0; g < 4; ++g){
            int g0 = (g << 7) + (w << 4) + (q << 2);
            float4v ma = *(const float4v*)(m2 + g0);
            float4v mb = *(const float4v*)(m2 + 512 + g0);
#pragma unroll
            for (int r4 = 0; r4 < 4; ++r4)
                acc[g][r4] += u0*ma[r4] + u1*mb[r4];
        }
    };

    // one elementwise pair (2 h-units): 14 trans + ~30 VALU, identical math
    // to the verified round-2 sequence
    auto elem_pair = [&](float4v (&acc)[4], float2v (&cst)[2], int p) -> float2v {
        float2v iv = {acc[0][2*p], acc[0][2*p + 1]};
        float2v fv = {acc[1][2*p], acc[1][2*p + 1]};
        float2v gv = {acc[2][2*p], acc[2][2*p + 1]};
        float2v ov = {acc[3][2*p], acc[3][2*p + 1]};
        float2v ei = v_exp2(iv);                  // e^{-i}
        float2v ef = v_exp2(fv);                  // e^{-f}
        float2v eg = v_exp2(gv);                  // e^{-2g}
        float2v pi_ = ei + one2;
        float2v pf  = ef + one2;
        float2v pg  = eg + one2;
        float2v mg  = one2 - eg;
        float2v t2  = pi_ * pg;
        float2v den = pf * t2;
        float2v num = v_fma(cst[p], t2, pf * mg);
        float2v c2  = num * v_rcp(den);
        float2v eo  = v_exp2(ov);                 // e^{-o}
        float2v ec  = v_exp2(c2 * sc22);          // e^{-2c2}
        float2v po  = eo + one2;
        float2v pc  = ec + one2;
        float2v mc  = one2 - ec;
        float2v h2  = mc * v_rcp(po * pc);
        cst[p] = c2;
        return h2;
    };

    auto finish_h = [&](float2v h0, float2v h1,
                        unsigned short (*lhp)[152], bool finalh, int hrow){
        bf16_4 hv;
        hv[0] = (__bf16)h0[0]; hv[1] = (__bf16)h0[1];
        hv[2] = (__bf16)h1[0]; hv[3] = (__bf16)h1[1];
        if (finalh){
            int cb = (w << 4) + (q << 2);
            hsh[hrow][cb]     = h0[0];
            hsh[hrow][cb + 1] = h0[1];
            hsh[hrow][cb + 2] = h1[0];
            hsh[hrow][cb + 3] = h1[1];
        }
        *(bf16_4*)&lhp[l][(w << 4) + (q << 2)] = hv;   // packed b64
    };

    // serial fallback (used where no next-tile gates exist)
    auto elem_write = [&](float4v (&acc)[4], float2v (&cst)[2],
                          unsigned short (*lhp)[152], bool finalh, int hrow){
        float2v h0 = elem_pair(acc, cst, 0);
        float2v h1 = elem_pair(acc, cst, 1);
        finish_h(h0, h1, lhp, finalh, hrow);
    };

    // FISSIONED region: gates(next tile) MFMAs in 8-instr chunks interleaved
    // with elem pairs of the current tile. Op-for-op identical math.
    auto gates_elem = [&](float4v (&accN)[4], bf16_8 (&bN)[4],
                          float4v (&accC)[4], float2v (&cstC)[2],
                          unsigned short (*lhp)[152], bool finalh, int hrow){
        // chunk 1: kt=0 (bias as C) + kt=1
#pragma unroll
        for (int g = 0; g < 4; ++g)
            accN[g] = __builtin_amdgcn_mfma_f32_16x16x32_bf16(wA[g][0], bN[0], bias4[g], 0, 0, 0);
#pragma unroll
        for (int g = 0; g < 4; ++g)
            accN[g] = __builtin_amdgcn_mfma_f32_16x16x32_bf16(wA[g][1], bN[1], accN[g], 0, 0, 0);
        float2v h0 = elem_pair(accC, cstC, 0);
        // chunk 2: kt=2 + kt=3
#pragma unroll
        for (int g = 0; g < 4; ++g)
            accN[g] = __builtin_amdgcn_mfma_f32_16x16x32_bf16(wA[g][2], bN[2], accN[g], 0, 0, 0);
#pragma unroll
        for (int g = 0; g < 4; ++g)
            accN[g] = __builtin_amdgcn_mfma_f32_16x16x32_bf16(wA[g][3], bN[3], accN[g], 0, 0, 0);
        float2v h1 = elem_pair(accC, cstC, 1);
        finish_h(h0, h1, lhp, finalh, hrow);
    };

    auto reload = [&](bf16_8 (&b)[4], const unsigned short (*lhp)[152]){
#pragma unroll
        for (int kt = 0; kt < 4; ++kt)
            b[kt] = *(const bf16_8*)&lhp[l][kt*32 + (q << 3)];
    };

    auto relout = [&](bf16_8 (&b)[4], int t, int batch){
        float4v r = {0.f, 0.f, 0.f, 0.f};
#pragma unroll
        for (int kt = 0; kt < 4; ++kt)
            r = __builtin_amdgcn_mfma_f32_16x16x32_bf16(wpA[kt], b[kt], r, 0, 0, 0);
        if (q == 0){
            float2v rv;
            rv[0] = r[0] + bp0;
            rv[1] = r[1] + bp1;
            *(float2v*)(out + t*(B_TOT*2) + (batch << 1)) = rv;
        }
    };

    // ---- step 0 peeled (rank-2 input corrections; serial) ----
    do_gates(accA, bA);
    u0fix(accA, l);
    do_gates(accB, bB);
    u0fix(accB, 16 + l);
    elem_write(accA, cstA, lhA, false, l);
    __syncthreads();
    reload(bA, lhA);
    if (w == 0) relout(bA, 0, batchA);

    // region 2 of step 0: gates(A,1) interleaved with elem(B,0)
    gates_elem(accA, bA, accB, cstB, lhB, false, 16 + l);
    __syncthreads();
    reload(bB, lhB);
    if (w == 4) relout(bB, 0, batchB);

    // ---- steps 1..31 ----
    for (int t = 1; t < SEQ; ++t){
        // region 1: gates(B,t) interleaved with elem(A,t)
        gates_elem(accB, bB, accA, cstA, lhA, t == SEQ - 1, l);
        __syncthreads();
        reload(bA, lhA);
        if (w == (t & 7)) relout(bA, t, batchA);
        // region 2: gates(A,t+1) interleaved with elem(B,t)
        if (t < SEQ - 1){
            gates_elem(accA, bA, accB, cstB, lhB, false, 16 + l);
        } else {
            elem_write(accB, cstB, lhB, true, 16 + l);
        }
        __syncthreads();
        reload(bB, lhB);
        if (w == ((t + 4) & 7)) relout(bB, t, batchB);
    }

    // ---- coalesced final-h store: LDS-staged, 32 rows x 128 cols ----
    __syncthreads();
    {
        int r = tid >> 4, c8 = (tid & 15) << 3;
        float4v v0 = *(const float4v*)&hsh[r][c8];
        float4v v1 = *(const float4v*)&hsh[r][c8 + 4];
        float* po = out + SEQ*B_TOT*2 + ((row0 + r) << 7) + c8;
        *(float4v*)po = v0;
        *(float4v*)(po + 4) = v1;
    }
}

extern "C" void kernel_launch(void* const* d_in, const int* in_sizes, int n_in,
                              void* d_out, int out_size, void* d_ws, size_t ws_size,
                              hipStream_t stream)
{
    (void)in_sizes; (void)n_in; (void)out_size; (void)ws_size;

    const float* lpr   = (const float*)d_in[1];
    const float* hh    = (const float*)d_in[2];
    const float* ch    = (const float*)d_in[3];
    const float* w_ih  = (const float*)d_in[5];
    const float* w_hh  = (const float*)d_in[6];
    const float* b_ih  = (const float*)d_in[7];
    const float* b_hh  = (const float*)d_in[8];
    const float* w_emb = (const float*)d_in[9];
    const float* b_emb = (const float*)d_in[10];
    const float* w_pos = (const float*)d_in[11];
    const float* b_pos = (const float*)d_in[12];

    unsigned short* weff  = (unsigned short*)d_ws;                     // 512*128 bf16
    float* beff           = (float*)((char*)d_ws + 131072);            // 512 f32
    float* m2             = (float*)((char*)d_ws + 131072 + 2048);     // 1024 f32
    unsigned short* wposA = (unsigned short*)((char*)d_ws + 131072 + 2048 + 4096); // 16*128 bf16

    hipLaunchKernelGGL(prep_kernel, dim3(1), dim3(512), 0, stream,
                       w_ih, w_hh, b_ih, b_hh, w_emb, b_emb, w_pos, b_pos,
                       weff, beff, m2, wposA);
    hipLaunchKernelGGL(dec_kernel, dim3(B_TOT/32), dim3(512), 0, stream,
                       lpr, hh, ch, b_pos, wposA, weff, beff, m2,
                       (float*)d_out);
}

// Round 6
// 491.309 us; speedup vs baseline: 1.2259x; 1.1431x over previous
//
#include <hip/hip_runtime.h>

#define B_TOT 65536
#define SEQ   32

typedef __bf16 bf16_8 __attribute__((ext_vector_type(8)));
typedef __bf16 bf16_4 __attribute__((ext_vector_type(4)));
typedef float  float4v __attribute__((ext_vector_type(4)));
typedef float  float2v __attribute__((ext_vector_type(2)));

#define SC1 (-1.4426950408889634f)   // -log2(e): i,f,o gate rows
#define SC2 (-2.8853900817779268f)   // -2*log2(e): g gate rows (and tanh(c2))

__device__ inline unsigned short f2bf(float f){
    unsigned u = __builtin_bit_cast(unsigned, f);
    u += 0x7FFFu + ((u >> 16) & 1u);           // round-to-nearest-even
    return (unsigned short)(u >> 16);
}

__device__ inline float2v v_exp2(float2v x){
    float2v r; r[0] = __builtin_amdgcn_exp2f(x[0]); r[1] = __builtin_amdgcn_exp2f(x[1]); return r;
}
__device__ inline float2v v_rcp(float2v x){
    float2v r; r[0] = __builtin_amdgcn_rcpf(x[0]); r[1] = __builtin_amdgcn_rcpf(x[1]); return r;
}
__device__ inline float2v v_fma(float2v a, float2v b, float2v c){
    float2v r; r[0] = __builtin_fmaf(a[0], b[0], c[0]); r[1] = __builtin_fmaf(a[1], b[1], c[1]); return r;
}

// ---- prep: W_eff = w_hh.T + w_pos.T @ (w_emb.T @ w_ih.T); biases folded;
// rows pre-scaled by -log2e (i,f,o) / -2log2e (g) so exp2 needs no mul. ----
__global__ void prep_kernel(const float* __restrict__ w_ih,
                            const float* __restrict__ w_hh,
                            const float* __restrict__ b_ih,
                            const float* __restrict__ b_hh,
                            const float* __restrict__ w_emb,
                            const float* __restrict__ b_emb,
                            const float* __restrict__ w_pos,
                            const float* __restrict__ b_pos,
                            unsigned short* __restrict__ weff,
                            float* __restrict__ beff,
                            float* __restrict__ m2,
                            unsigned short* __restrict__ wposA)
{
    int n = threadIdx.x;                       // 512 threads, one gate row each
    float m20 = 0.f, m21 = 0.f, bi = 0.f;
    for (int e = 0; e < 64; ++e){
        float wv = w_ih[n*64 + e];
        m20 += w_emb[e*2 + 0] * wv;
        m21 += w_emb[e*2 + 1] * wv;
        bi  += b_emb[e] * wv;
    }
    float sc = ((n >> 7) == 2) ? SC2 : SC1;    // gate order [i,f,g,o]
    m2[n]       = m20 * sc;
    m2[512 + n] = m21 * sc;
    beff[n] = (b_ih[n] + b_hh[n] + bi + b_pos[0]*m20 + b_pos[1]*m21) * sc;
    for (int k = 0; k < 128; ++k){
        float wv = w_hh[n*128 + k] + w_pos[k]*m20 + w_pos[128 + k]*m21;
        weff[n*128 + k] = f2bf(wv * sc);
    }
    if (n < 256) wposA[n] = f2bf(w_pos[n]);    // unscaled: rel path
    for (int idx = n; idx < 14*128; idx += 512) wposA[256 + idx] = 0;
}

// ---- main decoder: G^T = W_eff(A) x h^T(B); 16 rows/block, 4 waves.
// ROUND-2 STRUCTURE (best measured) + wave-slot anti-phasing: the two
// co-resident blocks per CU run identical deterministic code and phase-lock
// (MFMA phases collide on the matrix pipe, elem phases collide on the trans
// pipe). A one-time ~1600-cycle delay for waves in odd HW wave slots
// anti-phases the two blocks so one block's gate-MFMAs overlap the other's
// elementwise. Numerics untouched. ----
__global__ __launch_bounds__(256, 2) void dec_kernel(
    const float* __restrict__ lpr,             // (B,2)
    const float* __restrict__ hh,              // (B,128)
    const float* __restrict__ ch,              // (B,128)
    const float* __restrict__ b_pos,           // (2)
    const unsigned short* __restrict__ wposA,  // (16,128) bf16
    const unsigned short* __restrict__ weff,   // (512,128) bf16 pre-scaled
    const float* __restrict__ beff,            // (512) pre-scaled
    const float* __restrict__ m2,              // (2,512) pre-scaled
    float* __restrict__ out)                   // rels (32,B,2) ++ h (B,128)
{
    __shared__ __align__(16) unsigned short lh[2][16][152];  // stride 152: <=2-way banks
    __shared__ float ubuf[16][2];
    __shared__ __align__(16) float hsh[16][132];             // final-h staging

    const int tid  = threadIdx.x;
    const int w    = tid >> 6;
    const int lane = tid & 63;
    const int q    = lane >> 4;
    const int l    = lane & 15;
    const int row0 = blockIdx.x << 4;
    const int batch = row0 + l;

    const float2v one2 = {1.f, 1.f};
    const float2v sc22 = {SC2, SC2};

    // resident W_eff A-frags + bias float4s (bias used directly as MFMA C)
    bf16_8 wA[8][4];
    float4v bias4[8];
#pragma unroll
    for (int t8 = 0; t8 < 8; ++t8){
        int nbase = ((t8 >> 1) << 7) + 32*w + ((t8 & 1) << 4);
        int gA = nbase + l;
#pragma unroll
        for (int kt = 0; kt < 4; ++kt)
            wA[t8][kt] = *(const bf16_8*)(weff + (gA << 7) + kt*32 + (q << 3));
        bias4[t8] = *(const float4v*)(beff + nbase + (q << 2));
    }

    // w_pos A-frags (all waves; rel duty rotates)
    bf16_8 wpA[4];
#pragma unroll
    for (int kt = 0; kt < 4; ++kt)
        wpA[kt] = *(const bf16_8*)(wposA + (l << 7) + kt*32 + (q << 3));
    const float bp0 = b_pos[0], bp1 = b_pos[1];

    // c state: fp32 straight from global, kept as aligned pairs
    float2v cstp[2][2];
#pragma unroll
    for (int X = 0; X < 2; ++X){
        float4v cv = *(const float4v*)(ch + (batch << 7) + 32*w + 16*X + (q << 2));
        float2v clo = {cv[0], cv[1]};
        float2v chi = {cv[2], cv[3]};
        cstp[X][0] = clo;
        cstp[X][1] = chi;
    }

    // h0 B-frags straight from global (fp32 -> bf16)
    bf16_8 b[4];
#pragma unroll
    for (int kt = 0; kt < 4; ++kt){
        const float* ph = hh + (batch << 7) + kt*32 + (q << 3);
        float4v h0 = *(const float4v*)ph;
        float4v h1 = *(const float4v*)(ph + 4);
        bf16_8 t;
        t[0]=(__bf16)h0[0]; t[1]=(__bf16)h0[1]; t[2]=(__bf16)h0[2]; t[3]=(__bf16)h0[3];
        t[4]=(__bf16)h1[0]; t[5]=(__bf16)h1[1]; t[6]=(__bf16)h1[2]; t[7]=(__bf16)h1[3];
        b[kt] = t;
    }

    // wave0: r_{-1} = w_pos·h0 + b_pos ; u0' = lpr - r_{-1}
    if (w == 0){
        float4v r = {0.f, 0.f, 0.f, 0.f};
#pragma unroll
        for (int kt = 0; kt < 4; ++kt)
            r = __builtin_amdgcn_mfma_f32_16x16x32_bf16(wpA[kt], b[kt], r, 0, 0, 0);
        if (q == 0){
            float2v lp = *(const float2v*)(lpr + (batch << 1));
            ubuf[l][0] = lp[0] - (r[0] + bp0);
            ubuf[l][1] = lp[1] - (r[1] + bp1);
        }
    }
    __syncthreads();

    // ---- anti-phase: waves in odd HW wave slots (the co-resident sibling
    // block) start ~1600 cycles late. Intra-block barriers keep the block
    // coherent; the INTER-block offset persists across all 32 steps. ----
    {
        unsigned hwid;
        asm volatile("s_getreg_b32 %0, hwreg(HW_REG_HW_ID, 0, 4)" : "=s"(hwid));
        if (hwid & 1){
            __builtin_amdgcn_s_sleep(13);   // ~832 cyc
            __builtin_amdgcn_s_sleep(12);   // ~768 cyc  (total ~1600)
        }
    }

    float4v acc[8];

    auto do_gates = [&](){
#pragma unroll
        for (int t8 = 0; t8 < 8; ++t8)     // kt=0 consumes bias as C: free init
            acc[t8] = __builtin_amdgcn_mfma_f32_16x16x32_bf16(wA[t8][0], b[0], bias4[t8], 0, 0, 0);
#pragma unroll
        for (int kt = 1; kt < 4; ++kt)
#pragma unroll
            for (int t8 = 0; t8 < 8; ++t8)
                acc[t8] = __builtin_amdgcn_mfma_f32_16x16x32_bf16(wA[t8][kt], b[kt], acc[t8], 0, 0, 0);
    };

    // merged-reciprocal LSTM cell, pairwise on native v2f32 (verified round 2)
    auto do_elem_write = [&](int buf, bool finalh){
#pragma unroll
        for (int X = 0; X < 2; ++X){
            bf16_4 hv;
#pragma unroll
            for (int p = 0; p < 2; ++p){
                float2v iv = {acc[0 + X][2*p], acc[0 + X][2*p + 1]};
                float2v fv = {acc[2 + X][2*p], acc[2 + X][2*p + 1]};
                float2v gv = {acc[4 + X][2*p], acc[4 + X][2*p + 1]};
                float2v ov = {acc[6 + X][2*p], acc[6 + X][2*p + 1]};
                float2v ei = v_exp2(iv);                  // e^{-i}
                float2v ef = v_exp2(fv);                  // e^{-f}
                float2v eg = v_exp2(gv);                  // e^{-2g}
                float2v pi_ = ei + one2;
                float2v pf  = ef + one2;
                float2v pg  = eg + one2;
                float2v mg  = one2 - eg;
                float2v t2  = pi_ * pg;
                float2v den = pf * t2;
                float2v num = v_fma(cstp[X][p], t2, pf * mg);
                float2v c2  = num * v_rcp(den);
                float2v eo  = v_exp2(ov);                 // e^{-o}
                float2v ec  = v_exp2(c2 * sc22);          // e^{-2c2}
                float2v po  = eo + one2;
                float2v pc  = ec + one2;
                float2v mc  = one2 - ec;
                float2v h2  = mc * v_rcp(po * pc);
                cstp[X][p] = c2;
                hv[2*p]     = (__bf16)h2[0];
                hv[2*p + 1] = (__bf16)h2[1];
                if (finalh){
                    int cb = 32*w + 16*X + (q << 2) + 2*p;
                    hsh[l][cb]     = h2[0];
                    hsh[l][cb + 1] = h2[1];
                }
            }
            *(bf16_4*)&lh[buf][l][32*w + 16*X + (q << 2)] = hv;   // packed b64
        }
    };

    auto reload_and_rel = [&](int buf, int t){
#pragma unroll
        for (int kt = 0; kt < 4; ++kt)
            b[kt] = *(const bf16_8*)&lh[buf][l][kt*32 + (q << 3)];
        if (w == (t & 3)){                    // rotate rel duty across waves
            float4v r = {0.f, 0.f, 0.f, 0.f};
#pragma unroll
            for (int kt = 0; kt < 4; ++kt)
                r = __builtin_amdgcn_mfma_f32_16x16x32_bf16(wpA[kt], b[kt], r, 0, 0, 0);
            if (q == 0){
                float2v rv;
                rv[0] = r[0] + bp0;
                rv[1] = r[1] + bp1;
                *(float2v*)(out + t*(B_TOT*2) + (batch << 1)) = rv;
            }
        }
    };

    // ---- step 0 (peeled: rank-2 input correction along the gate dim) ----
    do_gates();
    {
        float u0 = ubuf[l][0], u1 = ubuf[l][1];
#pragma unroll
        for (int t8 = 0; t8 < 8; ++t8){
            int g0 = ((t8 >> 1) << 7) + 32*w + ((t8 & 1) << 4) + (q << 2);
            float4v ma = *(const float4v*)(m2 + g0);
            float4v mb = *(const float4v*)(m2 + 512 + g0);
#pragma unroll
            for (int r4 = 0; r4 < 4; ++r4)
                acc[t8][r4] += u0*ma[r4] + u1*mb[r4];
        }
    }
    do_elem_write(1, false);
    __syncthreads();
    reload_and_rel(1, 0);

    // ---- steps 1..31 ----
    for (int t = 1; t < SEQ; ++t){
        do_gates();
        do_elem_write((t + 1) & 1, t == SEQ - 1);
        __syncthreads();
        reload_and_rel((t + 1) & 1, t);
    }

    // ---- coalesced final-h store: LDS-staged, contiguous 32 B per thread ----
    __syncthreads();
    {
        int r = tid >> 4, c8 = (tid & 15) << 3;
        float4v v0 = *(const float4v*)&hsh[r][c8];
        float4v v1 = *(const float4v*)&hsh[r][c8 + 4];
        float* po = out + SEQ*B_TOT*2 + ((row0 + r) << 7) + c8;
        *(float4v*)po = v0;
        *(float4v*)(po + 4) = v1;
    }
}

extern "C" void kernel_launch(void* const* d_in, const int* in_sizes, int n_in,
                              void* d_out, int out_size, void* d_ws, size_t ws_size,
                              hipStream_t stream)
{
    (void)in_sizes; (void)n_in; (void)out_size; (void)ws_size;

    const float* lpr   = (const float*)d_in[1];
    const float* hh    = (const float*)d_in[2];
    const float* ch    = (const float*)d_in[3];
    const float* w_ih  = (const float*)d_in[5];
    const float* w_hh  = (const float*)d_in[6];
    const float* b_ih  = (const float*)d_in[7];
    const float* b_hh  = (const float*)d_in[8];
    const float* w_emb = (const float*)d_in[9];
    const float* b_emb = (const float*)d_in[10];
    const float* w_pos = (const float*)d_in[11];
    const float* b_pos = (const float*)d_in[12];

    unsigned short* weff  = (unsigned short*)d_ws;                     // 512*128 bf16
    float* beff           = (float*)((char*)d_ws + 131072);            // 512 f32
    float* m2             = (float*)((char*)d_ws + 131072 + 2048);     // 1024 f32
    unsigned short* wposA = (unsigned short*)((char*)d_ws + 131072 + 2048 + 4096); // 16*128 bf16

    hipLaunchKernelGGL(prep_kernel, dim3(1), dim3(512), 0, stream,
                       w_ih, w_hh, b_ih, b_hh, w_emb, b_emb, w_pos, b_pos,
                       weff, beff, m2, wposA);
    hipLaunchKernelGGL(dec_kernel, dim3(B_TOT/16), dim3(256), 0, stream,
                       lpr, hh, ch, b_pos, wposA, weff, beff, m2,
                       (float*)d_out);
}